// Round 1
// baseline (321.143 us; speedup 1.0000x reference)
//
#include <hip/hip_runtime.h>
#include <cstddef>

#define BB 8
#define CC 256
#define HH 128
#define WW 128
#define HW (HH*WW)          // 16384
#define CHW (CC*HH*WW)      // 4194304

// ---------------- Kernel A: 8x pooling along H and W (means) ----------------
// grid 2048 = (b*C+c), block 256
__global__ __launch_bounds__(256) void pool_kernel(
    const float* __restrict__ t1, const float* __restrict__ t2,
    float* __restrict__ keyH, float* __restrict__ keyW,
    float* __restrict__ valH, float* __restrict__ valW)
{
    const int bc = blockIdx.x;
    const int tid = threadIdx.x;
    const size_t base  = (size_t)bc * HW;
    const size_t pbase = (size_t)bc * 2048;

    const float* srcs[2] = { t1 + base, t2 + base };
    float* hdst[2] = { keyH + pbase, valH + pbase };
    float* wdst[2] = { keyW + pbase, valW + pbase };

    #pragma unroll
    for (int s = 0; s < 2; ++s) {
        const float* src = srcs[s];
        // H-pool: 512 tasks (k in 0..15, q in 0..31 float4 columns)
        float* hd = hdst[s];
        for (int t = tid; t < 512; t += 256) {
            const int k = t >> 5, q = t & 31;
            const float4* p = (const float4*)(src + (size_t)(k * 8) * WW) + q;
            float4 a = {0.f, 0.f, 0.f, 0.f};
            #pragma unroll
            for (int r = 0; r < 8; ++r) {
                float4 v = p[(size_t)r * (WW / 4)];
                a.x += v.x; a.y += v.y; a.z += v.z; a.w += v.w;
            }
            a.x *= 0.125f; a.y *= 0.125f; a.z *= 0.125f; a.w *= 0.125f;
            ((float4*)(hd + k * WW))[q] = a;
        }
        // W-pool: 2048 tasks (h in 0..127, k in 0..15)
        float* wd = wdst[s];
        for (int t = tid; t < 2048; t += 256) {
            const int h = t >> 4, k = t & 15;
            const float4* p = (const float4*)(src + (size_t)h * WW + k * 8);
            float4 a = p[0], b = p[1];
            wd[t] = (a.x + a.y + a.z + a.w + b.x + b.y + b.z + b.w) * 0.125f;
        }
    }
}

// ---------------- Kernel B: energies ----------------
// grid 512: b = bid&7 (XCD affinity for keyH L2 residency), hg = bid>>3 (h-pair)
// block 512: cq = tid>>7 (c quarter), w = tid&127
// Produces energy_H[b,h,k] fully; per-(h-pair) partials of energy_W into partW.
__global__ __launch_bounds__(512) void energy_kernel(
    const float* __restrict__ t2,
    const float* __restrict__ keyH, const float* __restrict__ keyW,
    float* __restrict__ energy, float* __restrict__ partW)
{
    const int bid = blockIdx.x;
    const int b   = bid & 7;
    const int hg  = bid >> 3;       // 0..63
    const int h0  = hg * 2;
    const int tid = threadIdx.x;
    const int cq  = tid >> 7;       // 0..3
    const int w   = tid & 127;

    const float* t2b = t2   + (size_t)b * CHW;
    const float* kHb = keyH + (size_t)b * (CC * 2048);
    const float* kWb = keyW + (size_t)b * (CC * 2048);

    float accH0[16], accH1[16], accW0[16], accW1[16];
    #pragma unroll
    for (int k = 0; k < 16; ++k) { accH0[k] = 0.f; accH1[k] = 0.f; accW0[k] = 0.f; accW1[k] = 0.f; }

    const int c0 = cq * 64;
    for (int ci = 0; ci < 64; ++ci) {
        const int c = c0 + ci;
        const float* trow = t2b + (size_t)c * HW + (size_t)h0 * WW + w;
        const float tA = trow[0];
        const float tB = trow[WW];

        const float* khc = kHb + (size_t)c * 2048 + w;          // + k*WW
        const float4* kwc = (const float4*)(kWb + (size_t)c * 2048 + h0 * 16);
        float kwA[16], kwB[16];
        *(float4*)&kwA[0]  = kwc[0]; *(float4*)&kwA[4]  = kwc[1];
        *(float4*)&kwA[8]  = kwc[2]; *(float4*)&kwA[12] = kwc[3];
        *(float4*)&kwB[0]  = kwc[4]; *(float4*)&kwB[4]  = kwc[5];
        *(float4*)&kwB[8]  = kwc[6]; *(float4*)&kwB[12] = kwc[7];

        #pragma unroll
        for (int k = 0; k < 16; ++k) {
            const float kv = khc[k * WW];
            accH0[k] += tA * kv;
            accH1[k] += tB * kv;
        }
        #pragma unroll
        for (int k = 0; k < 16; ++k) {
            accW0[k] += tA * kwA[k];
            accW1[k] += tB * kwB[k];
        }
    }

    // ---- reductions ----
    const int lane = tid & 63;
    const int wid  = tid >> 6;      // 0..7  (= cq*2 + w_half)
    __shared__ float sH[8][2][16];
    __shared__ float sW[4][128 * 17];

    #pragma unroll
    for (int g = 0; g < 2; ++g) {
        #pragma unroll
        for (int k = 0; k < 16; ++k) {
            float v = g ? accH1[k] : accH0[k];
            #pragma unroll
            for (int s = 32; s > 0; s >>= 1) v += __shfl_down(v, s);
            if (lane == 0) sH[wid][g][k] = v;
        }
    }
    #pragma unroll
    for (int k = 0; k < 16; ++k)
        sW[cq][w * 17 + k] = accW0[k] + accW1[k];
    __syncthreads();

    if (tid < 32) {
        const int g = tid >> 4, k = tid & 15;
        float s = 0.f;
        #pragma unroll
        for (int i = 0; i < 8; ++i) s += sH[i][g][k];
        energy[(size_t)b * 4096 + (size_t)(h0 + g) * 16 + k] = s;
    }
    for (int idx = tid; idx < 2048; idx += 512) {
        const int ww = idx >> 4, k = idx & 15;
        float s = sW[0][ww * 17 + k] + sW[1][ww * 17 + k]
                + sW[2][ww * 17 + k] + sW[3][ww * 17 + k];
        partW[((size_t)b * 64 + hg) * 2048 + idx] = s;
    }
}

// ---------------- Kernel B2: finish energy_W (sum over h-pairs) ----------------
// grid 64, block 256: one thread per (b,w,k)
__global__ __launch_bounds__(256) void energyW_reduce(
    const float* __restrict__ partW, float* __restrict__ energy)
{
    const int o = blockIdx.x * 256 + threadIdx.x;   // 0..16383
    const int b = o >> 11;
    const int rest = o & 2047;                       // w*16 + k
    const float* p = partW + (size_t)b * 64 * 2048 + rest;
    float s = 0.f;
    #pragma unroll 8
    for (int hg = 0; hg < 64; ++hg) s += p[(size_t)hg * 2048];
    energy[(size_t)b * 4096 + 2048 + rest] = s;
}

// ---------------- Kernel C: global min-max normalize + row softmax ----------------
// single block, 1024 threads; energy/att are [8][4096]
__global__ __launch_bounds__(1024) void softmax_kernel(
    const float* __restrict__ energy, float* __restrict__ att)
{
    const int tid = threadIdx.x;
    const int lane = tid & 63, wid = tid >> 6;      // 16 waves
    float4 v[8];
    float mn = 3.0e38f, mx = -3.0e38f;
    #pragma unroll
    for (int i = 0; i < 8; ++i) {
        v[i] = ((const float4*)energy)[i * 1024 + tid];   // iteration i == row i
        mn = fminf(mn, fminf(fminf(v[i].x, v[i].y), fminf(v[i].z, v[i].w)));
        mx = fmaxf(mx, fmaxf(fmaxf(v[i].x, v[i].y), fmaxf(v[i].z, v[i].w)));
    }
    __shared__ float smn[16], smx[16], sred[16], bcast[2];
    #pragma unroll
    for (int s = 32; s > 0; s >>= 1) {
        mn = fminf(mn, __shfl_down(mn, s));
        mx = fmaxf(mx, __shfl_down(mx, s));
    }
    if (lane == 0) { smn[wid] = mn; smx[wid] = mx; }
    __syncthreads();
    if (tid == 0) {
        float a = smn[0], m = smx[0];
        for (int i = 1; i < 16; ++i) { a = fminf(a, smn[i]); m = fmaxf(m, smx[i]); }
        bcast[0] = a; bcast[1] = m;
    }
    __syncthreads();
    const float gmn = bcast[0];
    const float inv = 1.0f / (bcast[1] - gmn);

    for (int i = 0; i < 8; ++i) {
        float4 e;
        e.x = __expf((v[i].x - gmn) * inv);
        e.y = __expf((v[i].y - gmn) * inv);
        e.z = __expf((v[i].z - gmn) * inv);
        e.w = __expf((v[i].w - gmn) * inv);
        float loc = e.x + e.y + e.z + e.w;
        #pragma unroll
        for (int s = 32; s > 0; s >>= 1) loc += __shfl_down(loc, s);
        if (lane == 0) sred[wid] = loc;
        __syncthreads();
        if (tid == 0) {
            float a = 0.f;
            for (int j = 0; j < 16; ++j) a += sred[j];
            bcast[0] = 1.0f / a;
        }
        __syncthreads();
        const float r = bcast[0];
        e.x *= r; e.y *= r; e.z *= r; e.w *= r;
        ((float4*)att)[i * 1024 + tid] = e;
        __syncthreads();
    }
}

// ---------------- Kernel D: recombination ----------------
// grid 2048 = (b = bid&7, c = bid>>3), block 128 (w)
// att_H[h,:] and val_W[h,:] use wave-uniform addresses -> scalar loads.
__global__ __launch_bounds__(128) void out_kernel(
    const float* __restrict__ t2,
    const float* __restrict__ valH, const float* __restrict__ valW,
    const float* __restrict__ att, float* __restrict__ out)
{
    const int bid = blockIdx.x;
    const int b = bid & 7;
    const int c = bid >> 3;
    const int w = threadIdx.x;
    const size_t pb = ((size_t)b * CC + c) * 2048;
    const float* vH  = valH + pb;
    const float* vW  = valW + pb;
    const float* aH  = att + (size_t)b * 4096;          // [h][16]
    const float* aWp = att + (size_t)b * 4096 + 2048;   // [w][16]
    const size_t tb = ((size_t)b * CC + c) * HW;
    const float* src = t2 + tb;
    float* dst = out + tb;

    float vHr[16];
    #pragma unroll
    for (int k = 0; k < 16; ++k) vHr[k] = vH[k * WW + w];

    float aWr[16];
    {
        const float4* p = (const float4*)(aWp + w * 16);
        float4 q0 = p[0], q1 = p[1], q2 = p[2], q3 = p[3];
        aWr[0]=q0.x; aWr[1]=q0.y; aWr[2]=q0.z; aWr[3]=q0.w;
        aWr[4]=q1.x; aWr[5]=q1.y; aWr[6]=q1.z; aWr[7]=q1.w;
        aWr[8]=q2.x; aWr[9]=q2.y; aWr[10]=q2.z; aWr[11]=q2.w;
        aWr[12]=q3.x; aWr[13]=q3.y; aWr[14]=q3.z; aWr[15]=q3.w;
    }

    for (int h = 0; h < HH; ++h) {
        const float* ah = aH + h * 16;    // uniform across wave
        const float* vw = vW + h * 16;    // uniform across wave
        float accH = 0.f, accW = 0.f;
        #pragma unroll
        for (int k = 0; k < 16; ++k) {
            accH += vHr[k] * ah[k];
            accW += aWr[k] * vw[k];
        }
        const float tv = src[(size_t)h * WW + w];
        dst[(size_t)h * WW + w] = 0.5f * (accH + accW) + tv;
    }
}

extern "C" void kernel_launch(void* const* d_in, const int* in_sizes, int n_in,
                              void* d_out, int out_size, void* d_ws, size_t ws_size,
                              hipStream_t stream)
{
    const float* t1 = (const float*)d_in[0];
    const float* t2 = (const float*)d_in[1];
    float* out = (float*)d_out;
    float* ws  = (float*)d_ws;

    float* keyH   = ws;                         // 4,194,304 floats
    float* keyW   = ws + (size_t)4194304;       // 4,194,304
    float* valH   = ws + (size_t)8388608;       // 4,194,304
    float* valW   = ws + (size_t)12582912;      // 4,194,304
    float* energy = ws + (size_t)16777216;      // 32,768
    float* att    = ws + (size_t)16777216 + 32768; // 32,768
    float* partW  = out;  // 1,048,576 floats of scratch; overwritten by out_kernel

    hipLaunchKernelGGL(pool_kernel,   dim3(2048), dim3(256),  0, stream,
                       t1, t2, keyH, keyW, valH, valW);
    hipLaunchKernelGGL(energy_kernel, dim3(512),  dim3(512),  0, stream,
                       t2, keyH, keyW, energy, partW);
    hipLaunchKernelGGL(energyW_reduce, dim3(64),  dim3(256),  0, stream,
                       partW, energy);
    hipLaunchKernelGGL(softmax_kernel, dim3(1),   dim3(1024), 0, stream,
                       energy, att);
    hipLaunchKernelGGL(out_kernel,    dim3(2048), dim3(128),  0, stream,
                       t2, valH, valW, att, out);
}

// Round 2
// 216.389 us; speedup vs baseline: 1.4841x; 1.4841x over previous
//
#include <hip/hip_runtime.h>
#include <cstddef>

#define CC 256
#define HH 128
#define WW 128
#define HW (HH*WW)          // 16384

typedef __attribute__((ext_vector_type(8))) short short8v;   // 8 bf16
typedef __attribute__((ext_vector_type(4))) float float4v;   // MFMA acc

__device__ __forceinline__ short f2bf(float x) {
    unsigned u = __float_as_uint(x);
    u += 0x7FFFu + ((u >> 16) & 1u);      // RNE to bf16
    return (short)(u >> 16);
}
__device__ __forceinline__ float4 add4(float4 a, float4 b) {
    float4 r; r.x=a.x+b.x; r.y=a.y+b.y; r.z=a.z+b.z; r.w=a.w+b.w; return r;
}
__device__ __forceinline__ float4 scale4(float4 a, float s) {
    float4 r; r.x=a.x*s; r.y=a.y*s; r.z=a.z*s; r.w=a.w*s; return r;
}
__device__ __forceinline__ float4 shflx4(float4 v, int m) {
    float4 r;
    r.x = __shfl_xor(v.x, m); r.y = __shfl_xor(v.y, m);
    r.z = __shfl_xor(v.z, m); r.w = __shfl_xor(v.w, m);
    return r;
}

// ============ Kernel 1: fused pooling + both energies (MFMA bf16) ============
// grid 1024: b = bid&7, chunk = bid>>3 (2 c's per block). block 512 (8 waves).
// Per c: t1 rows -> keyH[k][w], keyWT[k][h] (LDS only);
//        t2 rows -> valH/valWT global, t2 bf16 LDS [h][w] and [w][h];
//        MFMA: energy_H tile D[h][k] = t2 x keyH^T ; energy_W tile D[k][w] = keyWT x t2.
// Partials per block -> PH/PW, reduced by kernel 2.
__global__ __launch_bounds__(512) void fused_pool_energy(
    const float* __restrict__ t1, const float* __restrict__ t2,
    float* __restrict__ valH, float* __restrict__ valWT,
    float* __restrict__ PH, float* __restrict__ PW)
{
    // XOR-swizzled LDS (element-index swizzle: idx = row*stride + (col ^ ((row&7)<<3)))
    __shared__ __align__(16) short t2lds[64*128];   // [h_local][w]   16KB
    __shared__ __align__(16) short t2T  [128*64];   // [w][h_local]   16KB
    __shared__ __align__(16) short kH   [16*128];   // [k][w]          4KB
    __shared__ __align__(16) short kWT  [16*128];   // [k][h_global]   4KB
    __shared__ __align__(16) float vWs  [16*64];    // [k][h_local]    4KB

    const int bid   = blockIdx.x;
    const int b     = bid & 7;
    const int chunk = bid >> 3;            // 0..127
    const int c0    = chunk * 2;
    const int tid   = threadIdx.x;
    const int l     = tid & 63;
    const int v     = tid >> 6;            // wave 0..7
    const int w4    = l & 31;              // float4 column
    const int rq    = l >> 5;              // row quad within wave's 8 rows

    float4v accH = {0.f,0.f,0.f,0.f};      // wave v: H-tile v  (D[h][k])
    float4v accW = {0.f,0.f,0.f,0.f};      // wave v: W-tile v  (D[k][w])

    for (int ci = 0; ci < 2; ++ci) {
        const int c = c0 + ci;
        const size_t cbase = ((size_t)b * CC + c) * HW;

        // ---------- t1 pass: pool keys into LDS ----------
        #pragma unroll
        for (int half = 0; half < 2; ++half) {
            const int hbase = half*64 + v*8 + rq*4;
            const float4* src = (const float4*)(t1 + cbase + (size_t)hbase * WW) + w4;
            float4 x0 = src[0], x1 = src[32], x2 = src[64], x3 = src[96];
            // pool along H (k-group = wave's 8 rows)
            float4 s4 = add4(add4(x0,x1), add4(x2,x3));
            float4 m4 = scale4(add4(s4, shflx4(s4,32)), 0.125f);
            if (rq == 0) {
                const int k = half*8 + v;
                short4 p; p.x=f2bf(m4.x); p.y=f2bf(m4.y); p.z=f2bf(m4.z); p.w=f2bf(m4.w);
                *(short4*)&kH[k*128 + ((w4*4) ^ ((k&7)<<3))] = p;
            }
            // pool along W (pairs of float4 -> one value per 8 w)
            float rs0 = x0.x+x0.y+x0.z+x0.w, rs1 = x1.x+x1.y+x1.z+x1.w;
            float rs2 = x2.x+x2.y+x2.z+x2.w, rs3 = x3.x+x3.y+x3.z+x3.w;
            float o0 = __shfl_xor(rs0,1), o1 = __shfl_xor(rs1,1);
            float o2 = __shfl_xor(rs2,1), o3 = __shfl_xor(rs3,1);
            if ((l & 1) == 0) {
                const int kw = w4 >> 1;
                const int sw = (kw & 7) << 3;
                kWT[kw*128 + ((hbase+0) ^ sw)] = f2bf((rs0+o0)*0.125f);
                kWT[kw*128 + ((hbase+1) ^ sw)] = f2bf((rs1+o1)*0.125f);
                kWT[kw*128 + ((hbase+2) ^ sw)] = f2bf((rs2+o2)*0.125f);
                kWT[kw*128 + ((hbase+3) ^ sw)] = f2bf((rs3+o3)*0.125f);
            }
        }
        __syncthreads();

        // ---------- t2 halves: stage + MFMA ----------
        #pragma unroll
        for (int half = 0; half < 2; ++half) {
            const int hbase = half*64 + v*8 + rq*4;   // global h of first row
            const int hl4   = v*8 + rq*4;             // local h (0..63)
            const float4* src = (const float4*)(t2 + cbase + (size_t)hbase * WW) + w4;
            float4 x0 = src[0], x1 = src[32], x2 = src[64], x3 = src[96];

            // pool-H -> valH (global, fp32)
            float4 s4 = add4(add4(x0,x1), add4(x2,x3));
            float4 m4 = scale4(add4(s4, shflx4(s4,32)), 0.125f);
            if (rq == 0) {
                const int k = half*8 + v;
                *(float4*)&valH[((size_t)(b*CC + c)*16 + k)*128 + w4*4] = m4;
            }
            // pool-W -> stage
            {
                float rs0 = x0.x+x0.y+x0.z+x0.w, rs1 = x1.x+x1.y+x1.z+x1.w;
                float rs2 = x2.x+x2.y+x2.z+x2.w, rs3 = x3.x+x3.y+x3.z+x3.w;
                float o0 = __shfl_xor(rs0,1), o1 = __shfl_xor(rs1,1);
                float o2 = __shfl_xor(rs2,1), o3 = __shfl_xor(rs3,1);
                if ((l & 1) == 0) {
                    const int kw = w4 >> 1;
                    const int sw = (kw & 7) << 3;
                    vWs[kw*64 + ((hl4+0) ^ sw)] = (rs0+o0)*0.125f;
                    vWs[kw*64 + ((hl4+1) ^ sw)] = (rs1+o1)*0.125f;
                    vWs[kw*64 + ((hl4+2) ^ sw)] = (rs2+o2)*0.125f;
                    vWs[kw*64 + ((hl4+3) ^ sw)] = (rs3+o3)*0.125f;
                }
            }
            // bf16 convert + LDS stage (row-major and transposed)
            short s0x=f2bf(x0.x), s0y=f2bf(x0.y), s0z=f2bf(x0.z), s0w=f2bf(x0.w);
            short s1x=f2bf(x1.x), s1y=f2bf(x1.y), s1z=f2bf(x1.z), s1w=f2bf(x1.w);
            short s2x=f2bf(x2.x), s2y=f2bf(x2.y), s2z=f2bf(x2.z), s2w=f2bf(x2.w);
            short s3x=f2bf(x3.x), s3y=f2bf(x3.y), s3z=f2bf(x3.z), s3w=f2bf(x3.w);
            {
                short4 p;
                p.x=s0x; p.y=s0y; p.z=s0z; p.w=s0w;
                *(short4*)&t2lds[(hl4+0)*128 + ((w4*4) ^ (((hl4+0)&7)<<3))] = p;
                p.x=s1x; p.y=s1y; p.z=s1z; p.w=s1w;
                *(short4*)&t2lds[(hl4+1)*128 + ((w4*4) ^ (((hl4+1)&7)<<3))] = p;
                p.x=s2x; p.y=s2y; p.z=s2z; p.w=s2w;
                *(short4*)&t2lds[(hl4+2)*128 + ((w4*4) ^ (((hl4+2)&7)<<3))] = p;
                p.x=s3x; p.y=s3y; p.z=s3z; p.w=s3w;
                *(short4*)&t2lds[(hl4+3)*128 + ((w4*4) ^ (((hl4+3)&7)<<3))] = p;
            }
            {   // in-register 4x4 transpose -> t2T columns
                short4 p;
                int w = w4*4 + 0;
                p.x=s0x; p.y=s1x; p.z=s2x; p.w=s3x;
                *(short4*)&t2T[w*64 + (hl4 ^ (((w>>1)&7)<<3))] = p;
                w = w4*4 + 1;
                p.x=s0y; p.y=s1y; p.z=s2y; p.w=s3y;
                *(short4*)&t2T[w*64 + (hl4 ^ (((w>>1)&7)<<3))] = p;
                w = w4*4 + 2;
                p.x=s0z; p.y=s1z; p.z=s2z; p.w=s3z;
                *(short4*)&t2T[w*64 + (hl4 ^ (((w>>1)&7)<<3))] = p;
                w = w4*4 + 3;
                p.x=s0w; p.y=s1w; p.z=s2w; p.w=s3w;
                *(short4*)&t2T[w*64 + (hl4 ^ (((w>>1)&7)<<3))] = p;
            }
            __syncthreads();

            // ---- MFMA: H branch (waves whose h-tile lives in this half) ----
            if ((v >> 2) == half) {
                const int hl = (v & 3)*16 + (l & 15);
                const int kb = l & 15;
                #pragma unroll
                for (int ws2 = 0; ws2 < 4; ++ws2) {
                    const int wb = ws2*32 + (l>>4)*8;
                    short8v a  = *(const short8v*)&t2lds[hl*128 + (wb ^ ((hl&7)<<3))];
                    short8v bb = *(const short8v*)&kH  [kb*128 + (wb ^ ((kb&7)<<3))];
                    accH = __builtin_amdgcn_mfma_f32_16x16x32_bf16(a, bb, accH, 0, 0, 0);
                }
            }
            // ---- MFMA: W branch (all waves; wave v owns w-tile v) ----
            {
                const int kb = l & 15;
                const int w  = v*16 + (l & 15);
                #pragma unroll
                for (int hs = 0; hs < 2; ++hs) {
                    const int hloc = hs*32 + (l>>4)*8;
                    const int hg   = half*64 + hloc;
                    short8v a  = *(const short8v*)&kWT[kb*128 + (hg  ^ ((kb&7)<<3))];
                    short8v bb = *(const short8v*)&t2T[w*64   + (hloc ^ (((w>>1)&7)<<3))];
                    accW = __builtin_amdgcn_mfma_f32_16x16x32_bf16(a, bb, accW, 0, 0, 0);
                }
            }
            // ---- valWT global write (coalesced, from stage) ----
            {
                const int k0 = tid >> 6,          h0 = tid & 63;
                const int k1 = (tid+512) >> 6,    h1 = tid & 63;
                const size_t gb = (size_t)(b*CC + c) * 16;
                valWT[(gb + k0)*128 + half*64 + h0] = vWs[k0*64 + (h0 ^ ((k0&7)<<3))];
                valWT[(gb + k1)*128 + half*64 + h1] = vWs[k1*64 + (h1 ^ ((k1&7)<<3))];
            }
            __syncthreads();
        }
    }

    // ---------- write partials ----------
    {
        const size_t pb = ((size_t)(b*128 + chunk)) * 2048;
        #pragma unroll
        for (int r = 0; r < 4; ++r) {
            const int h = v*16 + (l>>4)*4 + r;
            PH[pb + h*16 + (l&15)] = accH[r];
            const int k = (l>>4)*4 + r;
            PW[pb + k*128 + v*16 + (l&15)] = accW[r];
        }
    }
}

// ============ Kernel 2: reduce partials -> energy[8][4096] ============
__global__ __launch_bounds__(256) void energy_reduce(
    const float* __restrict__ PH, const float* __restrict__ PW,
    float* __restrict__ energy)
{
    const int o = blockIdx.x*256 + threadIdx.x;   // 0..32767
    if (o < 16384) {
        const int b = o >> 11, i = o & 2047;      // i = h*16+k
        const float* p = PH + (size_t)b*128*2048 + i;
        float s = 0.f;
        #pragma unroll 8
        for (int j = 0; j < 128; ++j) s += p[(size_t)j*2048];
        energy[(size_t)b*4096 + i] = s;
    } else {
        const int oo = o - 16384;
        const int b = oo >> 11, i = oo & 2047;    // i = k*128+w
        const int k = i >> 7, w = i & 127;
        const float* p = PW + (size_t)b*128*2048 + i;
        float s = 0.f;
        #pragma unroll 8
        for (int j = 0; j < 128; ++j) s += p[(size_t)j*2048];
        energy[(size_t)b*4096 + 2048 + w*16 + k] = s;
    }
}

// ============ Kernel 3: global min-max normalize + row softmax ============
__global__ __launch_bounds__(1024) void softmax_kernel(
    const float* __restrict__ energy, float* __restrict__ att)
{
    const int tid = threadIdx.x;
    const int lane = tid & 63, wid = tid >> 6;      // 16 waves
    float4 v[8];
    float mn = 3.0e38f, mx = -3.0e38f;
    #pragma unroll
    for (int i = 0; i < 8; ++i) {
        v[i] = ((const float4*)energy)[i * 1024 + tid];
        mn = fminf(mn, fminf(fminf(v[i].x, v[i].y), fminf(v[i].z, v[i].w)));
        mx = fmaxf(mx, fmaxf(fmaxf(v[i].x, v[i].y), fmaxf(v[i].z, v[i].w)));
    }
    __shared__ float smn[16], smx[16], sred[16], bcast[2];
    #pragma unroll
    for (int s = 32; s > 0; s >>= 1) {
        mn = fminf(mn, __shfl_down(mn, s));
        mx = fmaxf(mx, __shfl_down(mx, s));
    }
    if (lane == 0) { smn[wid] = mn; smx[wid] = mx; }
    __syncthreads();
    if (tid == 0) {
        float a = smn[0], m = smx[0];
        for (int i = 1; i < 16; ++i) { a = fminf(a, smn[i]); m = fmaxf(m, smx[i]); }
        bcast[0] = a; bcast[1] = m;
    }
    __syncthreads();
    const float gmn = bcast[0];
    const float inv = 1.0f / (bcast[1] - gmn);

    for (int i = 0; i < 8; ++i) {
        float4 e;
        e.x = __expf((v[i].x - gmn) * inv);
        e.y = __expf((v[i].y - gmn) * inv);
        e.z = __expf((v[i].z - gmn) * inv);
        e.w = __expf((v[i].w - gmn) * inv);
        float loc = e.x + e.y + e.z + e.w;
        #pragma unroll
        for (int s = 32; s > 0; s >>= 1) loc += __shfl_down(loc, s);
        if (lane == 0) sred[wid] = loc;
        __syncthreads();
        if (tid == 0) {
            float a = 0.f;
            for (int j = 0; j < 16; ++j) a += sred[j];
            bcast[0] = 1.0f / a;
        }
        __syncthreads();
        const float r = bcast[0];
        e.x *= r; e.y *= r; e.z *= r; e.w *= r;
        ((float4*)att)[i * 1024 + tid] = e;
        __syncthreads();
    }
}

// ============ Kernel 4: recombination ============
// grid 2048 = (b = bid&7, c = bid>>3), block 128 (w)
__global__ __launch_bounds__(128) void out_kernel(
    const float* __restrict__ t2,
    const float* __restrict__ valH, const float* __restrict__ valWT,
    const float* __restrict__ att, float* __restrict__ out)
{
    const int bid = blockIdx.x;
    const int b = bid & 7;
    const int c = bid >> 3;
    const int w = threadIdx.x;
    const size_t pb = ((size_t)b * CC + c) * 2048;
    const float* vH  = valH  + pb;                      // [k][w]
    const float* vW  = valWT + pb;                      // [k][h]
    const float* aH  = att + (size_t)b * 4096;          // [h][16]
    const float* aWp = att + (size_t)b * 4096 + 2048;   // [w][16]
    const size_t tb = ((size_t)b * CC + c) * HW;
    const float* src = t2 + tb;
    float* dst = out + tb;

    float vHr[16];
    #pragma unroll
    for (int k = 0; k < 16; ++k) vHr[k] = vH[k * WW + w];

    float aWr[16];
    {
        const float4* p = (const float4*)(aWp + w * 16);
        float4 q0 = p[0], q1 = p[1], q2 = p[2], q3 = p[3];
        aWr[0]=q0.x; aWr[1]=q0.y; aWr[2]=q0.z; aWr[3]=q0.w;
        aWr[4]=q1.x; aWr[5]=q1.y; aWr[6]=q1.z; aWr[7]=q1.w;
        aWr[8]=q2.x; aWr[9]=q2.y; aWr[10]=q2.z; aWr[11]=q2.w;
        aWr[12]=q3.x; aWr[13]=q3.y; aWr[14]=q3.z; aWr[15]=q3.w;
    }

    for (int h = 0; h < HH; ++h) {
        const float* ah = aH + h * 16;      // wave-uniform
        const float* vw = vW + h;           // wave-uniform, stride 128
        float accH = 0.f, accW = 0.f;
        #pragma unroll
        for (int k = 0; k < 16; ++k) {
            accH += vHr[k] * ah[k];
            accW += aWr[k] * vw[k * 128];
        }
        const float tv = src[(size_t)h * WW + w];
        dst[(size_t)h * WW + w] = 0.5f * (accH + accW) + tv;
    }
}

extern "C" void kernel_launch(void* const* d_in, const int* in_sizes, int n_in,
                              void* d_out, int out_size, void* d_ws, size_t ws_size,
                              hipStream_t stream)
{
    const float* t1 = (const float*)d_in[0];
    const float* t2 = (const float*)d_in[1];
    float* out = (float*)d_out;
    float* ws  = (float*)d_ws;

    float* valH   = ws;                               //  4,194,304 floats
    float* valWT  = ws + (size_t)4194304;             //  4,194,304
    float* PH     = ws + (size_t)8388608;             //  2,097,152
    float* PW     = ws + (size_t)10485760;            //  2,097,152
    float* energy = ws + (size_t)12582912;            //     32,768
    float* att    = ws + (size_t)12615680;            //     32,768

    hipLaunchKernelGGL(fused_pool_energy, dim3(1024), dim3(512), 0, stream,
                       t1, t2, valH, valWT, PH, PW);
    hipLaunchKernelGGL(energy_reduce, dim3(128), dim3(256), 0, stream,
                       PH, PW, energy);
    hipLaunchKernelGGL(softmax_kernel, dim3(1), dim3(1024), 0, stream,
                       energy, att);
    hipLaunchKernelGGL(out_kernel, dim3(2048), dim3(128), 0, stream,
                       t2, valH, valWT, att, out);
}

// Round 3
// 179.740 us; speedup vs baseline: 1.7867x; 1.2039x over previous
//
#include <hip/hip_runtime.h>
#include <cstddef>

#define CC 256
#define HH 128
#define WW 128
#define HW (HH*WW)          // 16384

typedef __attribute__((ext_vector_type(8))) short short8v;   // 8 bf16
typedef __attribute__((ext_vector_type(4))) float float4v;   // MFMA acc

__device__ __forceinline__ short f2bf(float x) {
    unsigned u = __float_as_uint(x);
    u += 0x7FFFu + ((u >> 16) & 1u);      // RNE to bf16
    return (short)(u >> 16);
}
__device__ __forceinline__ float4 add4(float4 a, float4 b) {
    float4 r; r.x=a.x+b.x; r.y=a.y+b.y; r.z=a.z+b.z; r.w=a.w+b.w; return r;
}
__device__ __forceinline__ float4 scale4(float4 a, float s) {
    float4 r; r.x=a.x*s; r.y=a.y*s; r.z=a.z*s; r.w=a.w*s; return r;
}
__device__ __forceinline__ float4 shflx4(float4 v, int m) {
    float4 r;
    r.x = __shfl_xor(v.x, m); r.y = __shfl_xor(v.y, m);
    r.z = __shfl_xor(v.z, m); r.w = __shfl_xor(v.w, m);
    return r;
}

// ============ Kernel 1: fused pooling + both energies (MFMA bf16) ============
// grid 1024: b = bid&7, chunk = bid>>3 (2 c's per block). block 512 (8 waves).
__global__ __launch_bounds__(512) void fused_pool_energy(
    const float* __restrict__ t1, const float* __restrict__ t2,
    float* __restrict__ valH, float* __restrict__ valW,
    float* __restrict__ PH, float* __restrict__ PW)
{
    // XOR-swizzled LDS (element-index swizzle: idx = row*stride + (col ^ ((row&7)<<3)))
    __shared__ __align__(16) short t2lds[64*128];   // [h_local][w]   16KB
    __shared__ __align__(16) short t2T  [128*64];   // [w][h_local]   16KB
    __shared__ __align__(16) short kH   [16*128];   // [k][w]          4KB
    __shared__ __align__(16) short kWT  [16*128];   // [k][h_global]   4KB
    __shared__ __align__(16) float vWs  [16*64];    // [k][h_local]    4KB

    const int bid   = blockIdx.x;
    const int b     = bid & 7;
    const int chunk = bid >> 3;            // 0..127
    const int c0    = chunk * 2;
    const int tid   = threadIdx.x;
    const int l     = tid & 63;
    const int v     = tid >> 6;            // wave 0..7
    const int w4    = l & 31;              // float4 column
    const int rq    = l >> 5;              // row quad within wave's 8 rows

    float4v accH = {0.f,0.f,0.f,0.f};      // wave v: H-tile v  (D[h][k])
    float4v accW = {0.f,0.f,0.f,0.f};      // wave v: W-tile v  (D[k][w])

    for (int ci = 0; ci < 2; ++ci) {
        const int c = c0 + ci;
        const size_t cbase = ((size_t)b * CC + c) * HW;

        // ---------- t1 pass: pool keys into LDS ----------
        #pragma unroll
        for (int half = 0; half < 2; ++half) {
            const int hbase = half*64 + v*8 + rq*4;
            const float4* src = (const float4*)(t1 + cbase + (size_t)hbase * WW) + w4;
            float4 x0 = src[0], x1 = src[32], x2 = src[64], x3 = src[96];
            // pool along H (k-group = wave's 8 rows)
            float4 s4 = add4(add4(x0,x1), add4(x2,x3));
            float4 m4 = scale4(add4(s4, shflx4(s4,32)), 0.125f);
            if (rq == 0) {
                const int k = half*8 + v;
                short4 p; p.x=f2bf(m4.x); p.y=f2bf(m4.y); p.z=f2bf(m4.z); p.w=f2bf(m4.w);
                *(short4*)&kH[k*128 + ((w4*4) ^ ((k&7)<<3))] = p;
            }
            // pool along W (pairs of float4 -> one value per 8 w)
            float rs0 = x0.x+x0.y+x0.z+x0.w, rs1 = x1.x+x1.y+x1.z+x1.w;
            float rs2 = x2.x+x2.y+x2.z+x2.w, rs3 = x3.x+x3.y+x3.z+x3.w;
            float o0 = __shfl_xor(rs0,1), o1 = __shfl_xor(rs1,1);
            float o2 = __shfl_xor(rs2,1), o3 = __shfl_xor(rs3,1);
            if ((l & 1) == 0) {
                const int kw = w4 >> 1;
                const int sw = (kw & 7) << 3;
                kWT[kw*128 + ((hbase+0) ^ sw)] = f2bf((rs0+o0)*0.125f);
                kWT[kw*128 + ((hbase+1) ^ sw)] = f2bf((rs1+o1)*0.125f);
                kWT[kw*128 + ((hbase+2) ^ sw)] = f2bf((rs2+o2)*0.125f);
                kWT[kw*128 + ((hbase+3) ^ sw)] = f2bf((rs3+o3)*0.125f);
            }
        }
        __syncthreads();

        // ---------- t2 halves: stage + MFMA ----------
        #pragma unroll
        for (int half = 0; half < 2; ++half) {
            const int hbase = half*64 + v*8 + rq*4;   // global h of first row
            const int hl4   = v*8 + rq*4;             // local h (0..63)
            const float4* src = (const float4*)(t2 + cbase + (size_t)hbase * WW) + w4;
            float4 x0 = src[0], x1 = src[32], x2 = src[64], x3 = src[96];

            // pool-H -> valH (global, fp32)
            float4 s4 = add4(add4(x0,x1), add4(x2,x3));
            float4 m4 = scale4(add4(s4, shflx4(s4,32)), 0.125f);
            if (rq == 0) {
                const int k = half*8 + v;
                *(float4*)&valH[((size_t)(b*CC + c)*16 + k)*128 + w4*4] = m4;
            }
            // pool-W -> stage
            {
                float rs0 = x0.x+x0.y+x0.z+x0.w, rs1 = x1.x+x1.y+x1.z+x1.w;
                float rs2 = x2.x+x2.y+x2.z+x2.w, rs3 = x3.x+x3.y+x3.z+x3.w;
                float o0 = __shfl_xor(rs0,1), o1 = __shfl_xor(rs1,1);
                float o2 = __shfl_xor(rs2,1), o3 = __shfl_xor(rs3,1);
                if ((l & 1) == 0) {
                    const int kw = w4 >> 1;
                    const int sw = (kw & 7) << 3;
                    vWs[kw*64 + ((hl4+0) ^ sw)] = (rs0+o0)*0.125f;
                    vWs[kw*64 + ((hl4+1) ^ sw)] = (rs1+o1)*0.125f;
                    vWs[kw*64 + ((hl4+2) ^ sw)] = (rs2+o2)*0.125f;
                    vWs[kw*64 + ((hl4+3) ^ sw)] = (rs3+o3)*0.125f;
                }
            }
            // bf16 convert + LDS stage (row-major and transposed)
            short s0x=f2bf(x0.x), s0y=f2bf(x0.y), s0z=f2bf(x0.z), s0w=f2bf(x0.w);
            short s1x=f2bf(x1.x), s1y=f2bf(x1.y), s1z=f2bf(x1.z), s1w=f2bf(x1.w);
            short s2x=f2bf(x2.x), s2y=f2bf(x2.y), s2z=f2bf(x2.z), s2w=f2bf(x2.w);
            short s3x=f2bf(x3.x), s3y=f2bf(x3.y), s3z=f2bf(x3.z), s3w=f2bf(x3.w);
            {
                short4 p;
                p.x=s0x; p.y=s0y; p.z=s0z; p.w=s0w;
                *(short4*)&t2lds[(hl4+0)*128 + ((w4*4) ^ (((hl4+0)&7)<<3))] = p;
                p.x=s1x; p.y=s1y; p.z=s1z; p.w=s1w;
                *(short4*)&t2lds[(hl4+1)*128 + ((w4*4) ^ (((hl4+1)&7)<<3))] = p;
                p.x=s2x; p.y=s2y; p.z=s2z; p.w=s2w;
                *(short4*)&t2lds[(hl4+2)*128 + ((w4*4) ^ (((hl4+2)&7)<<3))] = p;
                p.x=s3x; p.y=s3y; p.z=s3z; p.w=s3w;
                *(short4*)&t2lds[(hl4+3)*128 + ((w4*4) ^ (((hl4+3)&7)<<3))] = p;
            }
            {   // in-register 4x4 transpose -> t2T columns
                short4 p;
                int w = w4*4 + 0;
                p.x=s0x; p.y=s1x; p.z=s2x; p.w=s3x;
                *(short4*)&t2T[w*64 + (hl4 ^ (((w>>1)&7)<<3))] = p;
                w = w4*4 + 1;
                p.x=s0y; p.y=s1y; p.z=s2y; p.w=s3y;
                *(short4*)&t2T[w*64 + (hl4 ^ (((w>>1)&7)<<3))] = p;
                w = w4*4 + 2;
                p.x=s0z; p.y=s1z; p.z=s2z; p.w=s3z;
                *(short4*)&t2T[w*64 + (hl4 ^ (((w>>1)&7)<<3))] = p;
                w = w4*4 + 3;
                p.x=s0w; p.y=s1w; p.z=s2w; p.w=s3w;
                *(short4*)&t2T[w*64 + (hl4 ^ (((w>>1)&7)<<3))] = p;
            }
            __syncthreads();

            // ---- MFMA: H branch (waves whose h-tile lives in this half) ----
            if ((v >> 2) == half) {
                const int hl = (v & 3)*16 + (l & 15);
                const int kb = l & 15;
                #pragma unroll
                for (int ws2 = 0; ws2 < 4; ++ws2) {
                    const int wb = ws2*32 + (l>>4)*8;
                    short8v a  = *(const short8v*)&t2lds[hl*128 + (wb ^ ((hl&7)<<3))];
                    short8v bb = *(const short8v*)&kH  [kb*128 + (wb ^ ((kb&7)<<3))];
                    accH = __builtin_amdgcn_mfma_f32_16x16x32_bf16(a, bb, accH, 0, 0, 0);
                }
            }
            // ---- MFMA: W branch (all waves; wave v owns w-tile v) ----
            {
                const int kb = l & 15;
                const int w  = v*16 + (l & 15);
                #pragma unroll
                for (int hs = 0; hs < 2; ++hs) {
                    const int hloc = hs*32 + (l>>4)*8;
                    const int hg   = half*64 + hloc;
                    short8v a  = *(const short8v*)&kWT[kb*128 + (hg  ^ ((kb&7)<<3))];
                    short8v bb = *(const short8v*)&t2T[w*64   + (hloc ^ (((w>>1)&7)<<3))];
                    accW = __builtin_amdgcn_mfma_f32_16x16x32_bf16(a, bb, accW, 0, 0, 0);
                }
            }
            // ---- valW global write ([h][k] layout, float2 per thread) ----
            {
                const int e = tid * 2;          // 1024 values this half
                const int h = e >> 4;           // local h 0..63
                const int k = e & 15;           // even k
                const size_t gb = (size_t)(b*CC + c) * 2048;
                float2 p;
                p.x = vWs[k*64     + (h ^ ((k&7)<<3))];
                p.y = vWs[(k+1)*64 + (h ^ (((k+1)&7)<<3))];
                *(float2*)&valW[gb + (size_t)(half*64 + h)*16 + k] = p;
            }
            __syncthreads();
        }
    }

    // ---------- write partials ----------
    {
        const size_t pb = ((size_t)(b*128 + chunk)) * 2048;
        #pragma unroll
        for (int r = 0; r < 4; ++r) {
            const int h = v*16 + (l>>4)*4 + r;
            PH[pb + h*16 + (l&15)] = accH[r];
            const int k = (l>>4)*4 + r;
            PW[pb + k*128 + v*16 + (l&15)] = accW[r];
        }
    }
}

// ============ Kernel 2: reduce partials -> energy[8][4096] ============
__global__ __launch_bounds__(256) void energy_reduce(
    const float* __restrict__ PH, const float* __restrict__ PW,
    float* __restrict__ energy)
{
    const int o = blockIdx.x*256 + threadIdx.x;   // 0..32767
    if (o < 16384) {
        const int b = o >> 11, i = o & 2047;      // i = h*16+k
        const float* p = PH + (size_t)b*128*2048 + i;
        float s = 0.f;
        #pragma unroll 8
        for (int j = 0; j < 128; ++j) s += p[(size_t)j*2048];
        energy[(size_t)b*4096 + i] = s;
    } else {
        const int oo = o - 16384;
        const int b = oo >> 11, i = oo & 2047;    // i = k*128+w
        const int k = i >> 7, w = i & 127;
        const float* p = PW + (size_t)b*128*2048 + i;
        float s = 0.f;
        #pragma unroll 8
        for (int j = 0; j < 128; ++j) s += p[(size_t)j*2048];
        energy[(size_t)b*4096 + 2048 + w*16 + k] = s;
    }
}

// ============ Kernel 3: global min-max normalize + row softmax ============
__global__ __launch_bounds__(1024) void softmax_kernel(
    const float* __restrict__ energy, float* __restrict__ att)
{
    const int tid = threadIdx.x;
    const int lane = tid & 63, wid = tid >> 6;      // 16 waves
    float4 v[8];
    float mn = 3.0e38f, mx = -3.0e38f;
    #pragma unroll
    for (int i = 0; i < 8; ++i) {
        v[i] = ((const float4*)energy)[i * 1024 + tid];
        mn = fminf(mn, fminf(fminf(v[i].x, v[i].y), fminf(v[i].z, v[i].w)));
        mx = fmaxf(mx, fmaxf(fmaxf(v[i].x, v[i].y), fmaxf(v[i].z, v[i].w)));
    }
    __shared__ float smn[16], smx[16], sred[16], bcast[2];
    #pragma unroll
    for (int s = 32; s > 0; s >>= 1) {
        mn = fminf(mn, __shfl_down(mn, s));
        mx = fmaxf(mx, __shfl_down(mx, s));
    }
    if (lane == 0) { smn[wid] = mn; smx[wid] = mx; }
    __syncthreads();
    if (tid == 0) {
        float a = smn[0], m = smx[0];
        for (int i = 1; i < 16; ++i) { a = fminf(a, smn[i]); m = fmaxf(m, smx[i]); }
        bcast[0] = a; bcast[1] = m;
    }
    __syncthreads();
    const float gmn = bcast[0];
    const float inv = 1.0f / (bcast[1] - gmn);

    for (int i = 0; i < 8; ++i) {
        float4 e;
        e.x = __expf((v[i].x - gmn) * inv);
        e.y = __expf((v[i].y - gmn) * inv);
        e.z = __expf((v[i].z - gmn) * inv);
        e.w = __expf((v[i].w - gmn) * inv);
        float loc = e.x + e.y + e.z + e.w;
        #pragma unroll
        for (int s = 32; s > 0; s >>= 1) loc += __shfl_down(loc, s);
        if (lane == 0) sred[wid] = loc;
        __syncthreads();
        if (tid == 0) {
            float a = 0.f;
            for (int j = 0; j < 16; ++j) a += sred[j];
            bcast[0] = 1.0f / a;
        }
        __syncthreads();
        const float r = bcast[0];
        e.x *= r; e.y *= r; e.z *= r; e.w *= r;
        ((float4*)att)[i * 1024 + tid] = e;
        __syncthreads();
    }
}

// ============ Kernel 4: recombination ============
// grid 8192 = (b = bid&7, hg = (bid>>3)&3, c = bid>>5), block 128 (w).
// h depends only on blockIdx + loop counter -> wave-uniform -> scalar loads
// of contiguous att_H[h][0..15] and valW[h][0..15] rows.
__global__ __launch_bounds__(128) void out_kernel(
    const float* __restrict__ t2,
    const float* __restrict__ valH, const float* __restrict__ valW,
    const float* __restrict__ att, float* __restrict__ out)
{
    const int bid = blockIdx.x;
    const int b  = bid & 7;
    const int hg = (bid >> 3) & 3;
    const int c  = bid >> 5;
    const int w  = threadIdx.x;
    const size_t pb = ((size_t)b * CC + c) * 2048;
    const float* vH = valH + pb;                        // [k][w]
    const float* vW = valW + pb;                        // [h][k]
    const float* aH = att + (size_t)b * 4096;           // [h][16]
    const float* aW = att + (size_t)b * 4096 + 2048;    // [w][16]
    const size_t tb = ((size_t)b * CC + c) * HW;

    float vHr[16];
    #pragma unroll
    for (int k = 0; k < 16; ++k) vHr[k] = vH[k * WW + w];

    float aWr[16];
    {
        const float4* p = (const float4*)(aW + w * 16);
        float4 q0 = p[0], q1 = p[1], q2 = p[2], q3 = p[3];
        aWr[0]=q0.x; aWr[1]=q0.y; aWr[2]=q0.z; aWr[3]=q0.w;
        aWr[4]=q1.x; aWr[5]=q1.y; aWr[6]=q1.z; aWr[7]=q1.w;
        aWr[8]=q2.x; aWr[9]=q2.y; aWr[10]=q2.z; aWr[11]=q2.w;
        aWr[12]=q3.x; aWr[13]=q3.y; aWr[14]=q3.z; aWr[15]=q3.w;
    }

    const int hbase = hg * 32;
    #pragma unroll 2
    for (int i = 0; i < 32; ++i) {
        const int h = hbase + i;
        const float tv = t2[tb + (size_t)h * WW + w];
        const float* ah = aH + h * 16;      // wave-uniform, contiguous 64B
        const float* vw = vW + h * 16;      // wave-uniform, contiguous 64B
        float accH = 0.f, accW = 0.f;
        #pragma unroll
        for (int k = 0; k < 16; ++k) {
            accH = fmaf(vHr[k], ah[k], accH);
            accW = fmaf(aWr[k], vw[k], accW);
        }
        out[tb + (size_t)h * WW + w] = 0.5f * (accH + accW) + tv;
    }
}

extern "C" void kernel_launch(void* const* d_in, const int* in_sizes, int n_in,
                              void* d_out, int out_size, void* d_ws, size_t ws_size,
                              hipStream_t stream)
{
    const float* t1 = (const float*)d_in[0];
    const float* t2 = (const float*)d_in[1];
    float* out = (float*)d_out;
    float* ws  = (float*)d_ws;

    float* valH   = ws;                               //  4,194,304 floats
    float* valW   = ws + (size_t)4194304;             //  4,194,304
    float* PH     = ws + (size_t)8388608;             //  2,097,152
    float* PW     = ws + (size_t)10485760;            //  2,097,152
    float* energy = ws + (size_t)12582912;            //     32,768
    float* att    = ws + (size_t)12615680;            //     32,768

    hipLaunchKernelGGL(fused_pool_energy, dim3(1024), dim3(512), 0, stream,
                       t1, t2, valH, valW, PH, PW);
    hipLaunchKernelGGL(energy_reduce, dim3(128), dim3(256), 0, stream,
                       PH, PW, energy);
    hipLaunchKernelGGL(softmax_kernel, dim3(1), dim3(1024), 0, stream,
                       energy, att);
    hipLaunchKernelGGL(out_kernel, dim3(8192), dim3(128), 0, stream,
                       t2, valH, valW, att, out);
}